// Round 4
// baseline (286.897 us; speedup 1.0000x reference)
//
#include <hip/hip_runtime.h>
#include <math.h>

#define NROWS 262144
#define NCOLS 128
#define TPB 256
#define NBLOCKS (NROWS / TPB)   // 1024

// One thread per row: stream 32 float4 of x and t, track running
// (argmax value, index, |x*t| at argmax) and running row sum. No cross-lane
// ops in the hot loop at all.
__global__ __launch_bounds__(TPB) void biased_loss_rows(
    const float* __restrict__ x, const float* __restrict__ t,
    float* __restrict__ partial)
{
    const int row = blockIdx.x * TPB + threadIdx.x;
    const float4* xr = (const float4*)(x + (size_t)row * NCOLS);
    const float4* tr = (const float4*)(t + (size_t)row * NCOLS);

    float acc0 = 0.f, acc1 = 0.f;
    float bv = -INFINITY; int bi = 0; float bc = 0.f;
    float t0 = 0.f;

    #pragma unroll
    for (int j = 0; j < NCOLS / 4; ++j) {
        const float4 xv = xr[j];
        const float4 tv = tr[j];
        if (j == 0) t0 = tv.x;

        const float c0 = fabsf(xv.x * tv.x);
        const float c1 = fabsf(xv.y * tv.y);
        const float c2 = fabsf(xv.z * tv.z);
        const float c3 = fabsf(xv.w * tv.w);
        acc0 += c0 + c1;
        acc1 += c2 + c3;

        // within-float4 argmax tree; strict '>' keeps the lower index on ties
        const bool s01 = xv.y > xv.x;
        const float v01 = s01 ? xv.y : xv.x;
        const int   i01 = 4 * j + (s01 ? 1 : 0);
        const float w01 = s01 ? c1 : c0;

        const bool s23 = xv.w > xv.z;
        const float v23 = s23 ? xv.w : xv.z;
        const int   i23 = 4 * j + 2 + (s23 ? 1 : 0);
        const float w23 = s23 ? c3 : c2;

        const bool sm = v23 > v01;            // tie keeps i01 (lower)
        const float vm = sm ? v23 : v01;
        const int   im = sm ? i23 : i01;
        const float wm = sm ? w23 : w01;

        const bool sb = vm > bv;              // tie keeps earlier j (lower)
        bv = sb ? vm : bv;
        bi = sb ? im : bi;
        bc = sb ? wm : bc;
    }

    const bool cond = (bi > 0) && (t0 == 0.0f);
    float rowsum = cond ? bc : (acc0 + acc1);

    // once-per-kernel wave reduction (6 steps), then block partial
    #pragma unroll
    for (int off = 32; off > 0; off >>= 1)
        rowsum += __shfl_xor(rowsum, off, 64);

    __shared__ float smem[TPB / 64];
    const int lane = threadIdx.x & 63, w = threadIdx.x >> 6;
    if (lane == 0) smem[w] = rowsum;
    __syncthreads();
    if (threadIdx.x == 0) {
        float b = 0.f;
        #pragma unroll
        for (int i = 0; i < TPB / 64; ++i) b += smem[i];
        partial[blockIdx.x] = b;
    }
}

__global__ __launch_bounds__(256) void reduce_partials(
    const float* __restrict__ partial, float* __restrict__ out, int n)
{
    float acc = 0.0f;
    for (int i = threadIdx.x; i < n; i += 256) acc += partial[i];
    #pragma unroll
    for (int off = 32; off > 0; off >>= 1)
        acc += __shfl_xor(acc, off, 64);
    __shared__ float smem[4];
    const int lane = threadIdx.x & 63, w = threadIdx.x >> 6;
    if (lane == 0) smem[w] = acc;
    __syncthreads();
    if (threadIdx.x == 0) {
        float s = smem[0] + smem[1] + smem[2] + smem[3];
        out[0] = s / (float)((size_t)NROWS * (size_t)NCOLS);
    }
}

extern "C" void kernel_launch(void* const* d_in, const int* in_sizes, int n_in,
                              void* d_out, int out_size, void* d_ws, size_t ws_size,
                              hipStream_t stream) {
    const float* x = (const float*)d_in[0];
    const float* t = (const float*)d_in[1];
    float* partial = (float*)d_ws;  // NBLOCKS * 4 B = 4 KiB scratch

    biased_loss_rows<<<NBLOCKS, TPB, 0, stream>>>(x, t, partial);
    reduce_partials<<<1, 256, 0, stream>>>(partial, (float*)d_out, NBLOCKS);
}

// Round 5
// 276.535 us; speedup vs baseline: 1.0375x; 1.0375x over previous
//
#include <hip/hip_runtime.h>
#include <math.h>
#include <stdint.h>

#define NROWS 262144
#define NCOLS 128
#define TILE_ROWS 64
#define TPB 256
#define NTILES (NROWS / TILE_ROWS)          // 4096 blocks
#define TILE_FLOATS (TILE_ROWS * NCOLS)     // 8192 floats = 32 KB per array
#define TILE_F4 (TILE_FLOATS / 4)           // 2048 float4s
#define F4_PER_THREAD (TILE_F4 / TPB)       // 8 DMA instrs per thread per array

// global -> LDS direct DMA, 16 B per lane. Per wave: uniform LDS base +
// lane*16, matching our linear thread->float4 mapping exactly.
__device__ __forceinline__ void dma16(const float* g, const float* l)
{
    __builtin_amdgcn_global_load_lds(
        (__attribute__((address_space(1))) void*)(uintptr_t)g,
        (__attribute__((address_space(3))) void*)(uint32_t)(uintptr_t)l,
        16, 0, 0);
}

__global__ __launch_bounds__(TPB) void biased_loss_tile(
    const float* __restrict__ x, const float* __restrict__ t,
    float* __restrict__ partial)
{
    __shared__ float smem[2 * TILE_FLOATS];   // xs | ts = 64 KB
    float* xs = smem;
    float* ts = smem + TILE_FLOATS;

    const int tid  = threadIdx.x;
    const int tile = blockIdx.x;
    const float* gx = x + (size_t)tile * TILE_FLOATS;
    const float* gt = t + (size_t)tile * TILE_FLOATS;

    // ---- stage: queue all 16 DMAs (64 KB) before any wait ----
    #pragma unroll
    for (int i = 0; i < F4_PER_THREAD; ++i) {
        const int f4 = i * TPB + tid;
        dma16(gx + 4 * f4, xs + 4 * f4);
    }
    #pragma unroll
    for (int i = 0; i < F4_PER_THREAD; ++i) {
        const int f4 = i * TPB + tid;
        dma16(gt + 4 * f4, ts + 4 * f4);
    }
    __syncthreads();   // vmcnt(0) drain + barrier: LDS tile valid

    // ---- process: 4 threads per row, 32 cols each ----
    // rotation (j + r) & 31 makes each ds_read_b32 2-way bank aliased (free).
    const int r = tid & 63;          // row within tile
    const int q = tid >> 6;          // column quarter
    const int rot = r & 31;
    const float* xrow = xs + r * NCOLS + q * 32;

    float bv = -INFINITY; int bi = 0x7fffffff; float bc = 0.f; float ps = 0.f;
    #pragma unroll
    for (int j = 0; j < 32; ++j) {
        const int c = (j + rot) & 31;
        const float xv = xrow[c];
        const float tv = xrow[c + TILE_FLOATS];   // same addr reg, imm offset
        const float p  = fabsf(xv * tv);
        ps += p;
        const int idx = q * 32 + c;
        // exact first-occurrence tie-break despite rotated visit order
        const bool take = (xv > bv) || (xv == bv && idx < bi);
        bv = take ? xv : bv;
        bi = take ? idx : bi;
        bc = take ? p  : bc;
    }

    __syncthreads();   // all reads of xs done before scratch overwrite

    // scratch aliases the first 4 KB of xs (ts region untouched)
    float* sv = smem;
    int*   si = (int*)(smem + 256);
    float* sc = smem + 512;
    float* ss = smem + 768;
    sv[tid] = bv; si[tid] = bi; sc[tid] = bc; ss[tid] = ps;
    __syncthreads();

    if (tid < 64) {   // threads 0-63 == all of wave 0
        float mbv = sv[tid]; int mbi = si[tid]; float mbc = sc[tid];
        float sum = ss[tid];
        #pragma unroll
        for (int qq = 1; qq < 4; ++qq) {
            const float ov = sv[qq * 64 + tid];
            const int   oi = si[qq * 64 + tid];
            const float oc = sc[qq * 64 + tid];
            sum += ss[qq * 64 + tid];
            const bool take = (ov > mbv) || (ov == mbv && oi < mbi);
            mbv = take ? ov : mbv;
            mbi = take ? oi : mbi;
            mbc = take ? oc : mbc;
        }
        const float t0 = ts[tid * NCOLS];          // target[row][0]
        const bool cond = (mbi > 0) && (t0 == 0.0f);
        float acc = cond ? mbc : sum;

        // full-wave butterfly over wave 0 (64 rows of this tile)
        #pragma unroll
        for (int off = 32; off > 0; off >>= 1)
            acc += __shfl_xor(acc, off, 64);
        if (tid == 0) partial[tile] = acc;
    }
}

__global__ __launch_bounds__(256) void reduce_partials(
    const float* __restrict__ partial, float* __restrict__ out, int n)
{
    float acc = 0.0f;
    for (int i = threadIdx.x; i < n; i += 256) acc += partial[i];
    #pragma unroll
    for (int off = 32; off > 0; off >>= 1)
        acc += __shfl_xor(acc, off, 64);
    __shared__ float smem[4];
    const int lane = threadIdx.x & 63, w = threadIdx.x >> 6;
    if (lane == 0) smem[w] = acc;
    __syncthreads();
    if (threadIdx.x == 0) {
        float s = smem[0] + smem[1] + smem[2] + smem[3];
        out[0] = s / (float)((size_t)NROWS * (size_t)NCOLS);
    }
}

extern "C" void kernel_launch(void* const* d_in, const int* in_sizes, int n_in,
                              void* d_out, int out_size, void* d_ws, size_t ws_size,
                              hipStream_t stream) {
    const float* x = (const float*)d_in[0];
    const float* t = (const float*)d_in[1];
    float* partial = (float*)d_ws;  // NTILES * 4 B = 16 KiB scratch

    biased_loss_tile<<<NTILES, TPB, 0, stream>>>(x, t, partial);
    reduce_partials<<<1, 256, 0, stream>>>(partial, (float*)d_out, NTILES);
}

// Round 7
// 252.340 us; speedup vs baseline: 1.1369x; 1.0959x over previous
//
#include <hip/hip_runtime.h>

#define NROWS 262144
#define NCOLS 128
#define TPB 256
#define WPB (TPB / 64)
#define NBLOCKS 4096
#define NWAVES (NBLOCKS * WPB)           // 16384 waves
#define NPAIRS (NROWS / 2)               // 131072
#define U 2                              // pairs batched per load phase
#define NBATCH (NPAIRS / (NWAVES * U))   // 4 batches per wave

typedef float floatx4 __attribute__((ext_vector_type(4)));

__device__ __forceinline__ floatx4 ntload4(const float* p)
{
    return __builtin_nontemporal_load((const floatx4*)p);
}

// Lanes 0-31 -> row 2p, lanes 32-63 -> row 2p+1; each lane loads one float4
// of x and t (wave covers 1KB contiguous per array per pair). U=2 pairs'
// loads are issued back-to-back (4 nt loads in flight) before processing.
// Non-temporal: fetches stream past L2/L3 without allocating, so they do
// not force dirty-victim writebacks of the harness's restore data.
__global__ __launch_bounds__(TPB) void biased_loss_partial(
    const float* __restrict__ x, const float* __restrict__ t,
    float* __restrict__ partial)
{
    const int lane = threadIdx.x & 63;
    const int waveInBlock = threadIdx.x >> 6;
    const int gw = blockIdx.x * WPB + waveInBlock;
    const int half = lane >> 5;
    const int sub  = lane & 31;

    float acc = 0.0f;

    #pragma unroll
    for (int b = 0; b < NBATCH; ++b) {
        const int pbase = (b * NWAVES + gw) * U;   // U consecutive pairs

        floatx4 xv[U], tv[U];
        #pragma unroll
        for (int u = 0; u < U; ++u) {
            const size_t base =
                (size_t)(2 * (pbase + u) + half) * NCOLS + (size_t)sub * 4;
            xv[u] = ntload4(x + base);
            tv[u] = ntload4(t + base);
        }

        #pragma unroll
        for (int u = 0; u < U; ++u) {
            const int c = sub * 4;
            float bv = xv[u].x; int bi = c;
            if (xv[u].y > bv) { bv = xv[u].y; bi = c + 1; }
            if (xv[u].z > bv) { bv = xv[u].z; bi = c + 2; }
            if (xv[u].w > bv) { bv = xv[u].w; bi = c + 3; }

            // butterfly argmax across the 32-lane half (off<=16 stays in half)
            #pragma unroll
            for (int off = 16; off > 0; off >>= 1) {
                float ov = __shfl_xor(bv, off, 64);
                int   oi = __shfl_xor(bi, off, 64);
                if (ov > bv || (ov == bv && oi < bi)) { bv = ov; bi = oi; }
            }

            float t0 = __shfl(tv[u].x, half << 5, 64);
            const bool cond = (bi > 0) && (t0 == 0.0f);

            float c0 = fabsf(xv[u].x * tv[u].x);
            float c1 = fabsf(xv[u].y * tv[u].y);
            float c2 = fabsf(xv[u].z * tv[u].z);
            float c3 = fabsf(xv[u].w * tv[u].w);

            float s;
            if (cond) {
                s = (c     == bi ? c0 : 0.0f)
                  + (c + 1 == bi ? c1 : 0.0f)
                  + (c + 2 == bi ? c2 : 0.0f)
                  + (c + 3 == bi ? c3 : 0.0f);
            } else {
                s = (c0 + c1) + (c2 + c3);
            }
            acc += s;
        }
    }

    // full-wave sum
    #pragma unroll
    for (int off = 32; off > 0; off >>= 1)
        acc += __shfl_xor(acc, off, 64);

    __shared__ float smem[WPB];
    if (lane == 0) smem[waveInBlock] = acc;
    __syncthreads();
    if (threadIdx.x == 0) {
        float bsum = 0.0f;
        #pragma unroll
        for (int w = 0; w < WPB; ++w) bsum += smem[w];
        partial[blockIdx.x] = bsum;
    }
}

__global__ __launch_bounds__(256) void reduce_partials(
    const float* __restrict__ partial, float* __restrict__ out, int n)
{
    float acc = 0.0f;
    for (int i = threadIdx.x; i < n; i += 256) acc += partial[i];
    #pragma unroll
    for (int off = 32; off > 0; off >>= 1)
        acc += __shfl_xor(acc, off, 64);
    __shared__ float smem[4];
    const int lane = threadIdx.x & 63, w = threadIdx.x >> 6;
    if (lane == 0) smem[w] = acc;
    __syncthreads();
    if (threadIdx.x == 0) {
        float s = smem[0] + smem[1] + smem[2] + smem[3];
        out[0] = s / (float)((size_t)NROWS * (size_t)NCOLS);
    }
}

extern "C" void kernel_launch(void* const* d_in, const int* in_sizes, int n_in,
                              void* d_out, int out_size, void* d_ws, size_t ws_size,
                              hipStream_t stream) {
    const float* x = (const float*)d_in[0];
    const float* t = (const float*)d_in[1];
    float* partial = (float*)d_ws;  // NBLOCKS * 4 B = 16 KiB scratch

    biased_loss_partial<<<NBLOCKS, TPB, 0, stream>>>(x, t, partial);
    reduce_partials<<<1, 256, 0, stream>>>(partial, (float*)d_out, NBLOCKS);
}